// Round 10
// baseline (179.208 us; speedup 1.0000x reference)
//
#include <hip/hip_runtime.h>
#include <math.h>

static constexpr int B_  = 2;
static constexpr int S_  = 2048;
static constexpr int E_  = 1024;
static constexpr int NH_ = 4;
static constexpr int HD_ = 256;
static constexpr int BH_ = B_ * NH_;

typedef __attribute__((ext_vector_type(8))) _Float16 half8;
typedef __attribute__((ext_vector_type(4))) float    f32x4;
typedef __attribute__((ext_vector_type(4))) _Float16 half4v;

// Fragment-major layouts (written by prep, read by mlstm as coalesced 1 KB lines):
//  Q/K per bh: frag(rb16 = s>>4, kk = d>>5) at ((rb16*8 + kk)*512) halfs;
//              lane l = (s&15) + (((d&31)>>3)<<4) holds halfs j = d&7.
//  V^T per bh: frag(ktile = s>>6, dblk = d>>4, kb = (s&63)>>5) at
//              (((ktile*16 + dblk)*2 + kb)*512) halfs; lane l = (d&15) + (((s&31)>>3)<<4), j = s&7.

__device__ __forceinline__ int wofs(int e) { return (e << 4) ^ ((e & 0x38) << 1); }

// ---------------- Kernel 1: gates + fp16 Q/K (frag-major) + V frag-transpose (unchanged) ----------------
__global__ __launch_bounds__(1024) void prep_kernel(
    const float* __restrict__ q, const float* __restrict__ k, const float* __restrict__ v,
    const float* __restrict__ igk, const float* __restrict__ igb,
    const float* __restrict__ fgk, const float* __restrict__ fgb,
    float* __restrict__ ig_out, float* __restrict__ fg_out,
    _Float16* __restrict__ Qh, _Float16* __restrict__ Kh, _Float16* __restrict__ Vt)
{
    __shared__ __align__(16) char PSM[98304];
    char* wiB = PSM;            // 48 KB, swizzled float4 per element
    char* wfB = PSM + 49152;

    const int t = threadIdx.x;
    #pragma unroll
    for (int i = 0; i < 3; ++i) {
        int e = t + 1024 * i;
        *(float4*)(wiB + wofs(e)) = ((const float4*)igk)[e];
        *(float4*)(wfB + wofs(e)) = ((const float4*)fgk)[e];
    }
    __syncthreads();

    const int wave = t >> 6;
    const int l    = t & 63;
    const int bs   = blockIdx.x * 16 + wave;     // b*S + s
    const int b = bs >> 11, s = bs & (S_ - 1);
    const float* qrow = q + (size_t)bs * E_;
    const float* krow = k + (size_t)bs * E_;
    const float* vrow = v + (size_t)bs * E_;

    float accI[4] = {0.f,0.f,0.f,0.f}, accF[4] = {0.f,0.f,0.f,0.f};
    #pragma unroll
    for (int j = 0; j < 12; ++j) {
        const int e4 = l * 4 + 256 * j;          // 4 consecutive elements of gate_in
        float4 g4;
        if (j < 4)       g4 = *(const float4*)(qrow + e4);
        else if (j < 8)  g4 = *(const float4*)(krow + (e4 - E_));
        else             g4 = *(const float4*)(vrow + (e4 - 2 * E_));
        const float ge[4] = {g4.x, g4.y, g4.z, g4.w};
        if (j < 4) {
            const int d = e4 & 255, hh = e4 >> 8;
            const int idx = ((s >> 4) * 8 + (d >> 5)) * 512
                          + (s & 15) * 8 + (((d & 31) >> 3) << 7) + (d & 7);
            half4v st;
            st.x = (_Float16)(ge[0] * 0.0625f); st.y = (_Float16)(ge[1] * 0.0625f);
            st.z = (_Float16)(ge[2] * 0.0625f); st.w = (_Float16)(ge[3] * 0.0625f);
            *(half4v*)(Qh + ((size_t)(b * NH_ + hh)) * (S_ * HD_) + idx) = st;
        } else if (j < 8) {
            const int e2 = e4 - E_;
            const int d = e2 & 255, hh = e2 >> 8;
            const int idx = ((s >> 4) * 8 + (d >> 5)) * 512
                          + (s & 15) * 8 + (((d & 31) >> 3) << 7) + (d & 7);
            half4v st;
            st.x = (_Float16)ge[0]; st.y = (_Float16)ge[1];
            st.z = (_Float16)ge[2]; st.w = (_Float16)ge[3];
            *(half4v*)(Kh + ((size_t)(b * NH_ + hh)) * (S_ * HD_) + idx) = st;
        }
        #pragma unroll
        for (int i = 0; i < 4; ++i) {
            float4 wiv = *(const float4*)(wiB + wofs(e4 + i));
            float4 wfv = *(const float4*)(wfB + wofs(e4 + i));
            accI[0] = fmaf(ge[i], wiv.x, accI[0]); accI[1] = fmaf(ge[i], wiv.y, accI[1]);
            accI[2] = fmaf(ge[i], wiv.z, accI[2]); accI[3] = fmaf(ge[i], wiv.w, accI[3]);
            accF[0] = fmaf(ge[i], wfv.x, accF[0]); accF[1] = fmaf(ge[i], wfv.y, accF[1]);
            accF[2] = fmaf(ge[i], wfv.z, accF[2]); accF[3] = fmaf(ge[i], wfv.w, accF[3]);
        }
    }
    #pragma unroll
    for (int m = 1; m < 64; m <<= 1) {
        #pragma unroll
        for (int h = 0; h < 4; ++h) {
            accI[h] += __shfl_xor(accI[h], m);
            accF[h] += __shfl_xor(accF[h], m);
        }
    }
    if (l == 0) {
        #pragma unroll
        for (int h = 0; h < 4; ++h) {
            ig_out[((size_t)(b * NH_ + h)) * S_ + s] = accI[h] + igb[h];
            fg_out[((size_t)(b * NH_ + h)) * S_ + s] = accF[h] + fgb[h];
        }
    }

    __syncthreads();    // all weight reads done; reuse LDS for V transpose
    {
        float (*tile)[65] = (float(*)[65])(PSM + (t >> 8) * 16640);
        const int tid = t & 255;
        const int m  = blockIdx.x * 4 + (t >> 8);    // 0..1023 tile jobs
        const int bh = m & 7;
        const int sb = (m >> 3) & 31;                // ktile
        const int db = m >> 8;                       // d block of 64
        const int bb = bh >> 2, hh = bh & 3;
        const int j4 = (tid & 15) * 4;
        const int i0 = tid >> 4;
        const float* src = v + ((size_t)(bb * S_ + sb * 64)) * E_ + hh * HD_ + db * 64;
        #pragma unroll
        for (int p = 0; p < 4; ++p) {
            int i = i0 + p * 16;
            float4 val = *(const float4*)(src + (size_t)i * E_ + j4);
            tile[i][j4] = val.x; tile[i][j4+1] = val.y; tile[i][j4+2] = val.z; tile[i][j4+3] = val.w;
        }
        __syncthreads();
        const int ll = tid & 63;
        const int sw_ = tid >> 6;
        _Float16* dstb = Vt + (size_t)bh * (S_ * HD_);
        #pragma unroll
        for (int kb = 0; kb < 2; ++kb) {
            half8 pk;
            #pragma unroll
            for (int jj = 0; jj < 8; ++jj)
                pk[jj] = (_Float16)tile[kb * 32 + (ll >> 4) * 8 + jj][sw_ * 16 + (ll & 15)];
            *(half8*)(dstb + ((size_t)((sb * 16 + db * 4 + sw_) * 2 + kb)) * 512 + ll * 8) = pk;
        }
    }
}

// ---------------- Kernel 2 (R10): Q-in-LDS, <=128 regs/wave, true 2 blocks/CU ----------------
// R9 post-mortem: V-through-LDS cost 1K cy/tile LDS traffic at 2 waves/SIMD = net loss (clean
// counters, +17us). Arc insight: every "2 blocks/CU" attempt either never co-resided (R4/R6:
// (512,2) lets regs >128 -> 1 block/CU; occupancy ~18% all along) or spilled (R2/R8 at ~200
// live vs 128 cap). TLP was never actually tested. R10 sheds exactly qf (64 regs) by staging
// Q once per block into LDS (16 KB) and reading it JIT inside the QK MFMA loop -> per-wave
// liveness ~120 <= 128 -> __launch_bounds__(512,4) fits -> real 2 blocks/CU, 4 waves/SIMD.
// Grid 512: one row-block per block, rb = s<32 ? s : 63-(s-32) (complementary light/heavy
// per XCD; dynamic backfill smooths residual imbalance). K/V in regs exactly as R7.
static constexpr int OFF_PB  = 16384;                  // qlds [16 frag][1024 B] at 0
static constexpr int OFF_G   = OFF_PB + 16384;         // Pb [2][32 rows][256 B] swizzled
static constexpr int OFF_A2  = OFF_G + S_ * 4;         // sG [S]
static constexpr int OFF_M2  = OFF_A2 + 128;           // amM2 [32]
static constexpr int OFF_RS  = OFF_M2 + 128;           // sM2 [32]
static constexpr int OFF_SS  = OFF_RS + 1024;          // rsumP [8][32]
static constexpr int OFF_WR  = OFF_SS + 1024;          // ssP [8][32]
static constexpr int SMB     = OFF_WR + 64;            // 43328 B (2 blocks = 86.7 KB < 160)

#define TILE_BODY(MASKED)                                                     \
{                                                                             \
    /* V fragments for THIS tile (consumed after the barrier) */              \
    {                                                                         \
        const _Float16* vb_ = Vtp + (size_t)jt * 32768 + l * 8;               \
        _Pragma("unroll")                                                     \
        for (int dn = 0; dn < 2; ++dn) {                                      \
            _Pragma("unroll")                                                 \
            for (int k0 = 0; k0 < 4; ++k0)                                    \
                vf[dn * 4 + k0] = *(const half8*)(vb_                         \
                    + (((k0 >> 1) * 16 + w * 2 + dn) * 2 + (k0 & 1)) * 512);  \
        }                                                                     \
    }                                                                         \
    /* swapped QK^T: D[k][q]; Q fragments JIT from LDS (contiguous 1 KB = conflict-free) */ \
    f32x4 s0 = (f32x4){0.f,0.f,0.f,0.f}, s1 = (f32x4){0.f,0.f,0.f,0.f};      \
    __builtin_amdgcn_s_setprio(1);                                            \
    _Pragma("unroll")                                                         \
    for (int kk = 0; kk < 8; ++kk) {                                          \
        half8 q0 = *(const half8*)(qlds + kk * 1024 + l * 16);                \
        half8 q1 = *(const half8*)(qlds + (kk + 8) * 1024 + l * 16);          \
        s0 = __builtin_amdgcn_mfma_f32_16x16x32_f16(kf[kk], q0, s0, 0, 0, 0); \
        s1 = __builtin_amdgcn_mfma_f32_16x16x32_f16(kf[kk], q1, s1, 0, 0, 0); \
    }                                                                         \
    __builtin_amdgcn_s_setprio(0);                                            \
    if (!MASKED) {  /* kf refill for next tile; stays in flight across barrier */ \
        const _Float16* kb_ = Kp + ((size_t)((jt + 1) * 8 + w) * 8) * 512 + l * 8; \
        _Pragma("unroll")                                                     \
        for (int kk = 0; kk < 8; ++kk) kf[kk] = *(const half8*)(kb_ + kk * 512); \
    }                                                                         \
    /* fixup: p = s * exp2(amM[q] + G2[k]); mask only on diagonal tile */     \
    {                                                                         \
        float4 gv4 = *(const float4*)(sG + jt * 128 + w * 16 + quad * 4);     \
        const float gvv[4] = {gv4.x, gv4.y, gv4.z, gv4.w};                    \
        char* pbC = Pb + (jt & 1) * 8192;                                     \
        half4v h0, h1;                                                        \
        _Pragma("unroll")                                                     \
        for (int rr = 0; rr < 4; ++rr) {                                      \
            float p0 = s0[rr] * __builtin_amdgcn_exp2f(amM0 + gvv[rr]);       \
            float p1 = s1[rr] * __builtin_amdgcn_exp2f(amM1 + gvv[rr]);       \
            if (MASKED) {                                                     \
                const int gc = jt * 128 + w * 16 + quad * 4 + rr;             \
                p0 = (gc <= rowbase + col) ? p0 : 0.f;                        \
                p1 = (gc <= rowbase + 16 + col) ? p1 : 0.f;                   \
            }                                                                 \
            rs0 += p0; rs1 += p1;                                             \
            h0[rr] = (_Float16)p0; h1[rr] = (_Float16)p1;                     \
        }                                                                     \
        const int wb = (w * 32 + quad * 8) ^ ((col & 7) << 4);                \
        *(half4v*)(pbC + col * 256 + wb) = h0;                                \
        *(half4v*)(pbC + (16 + col) * 256 + wb) = h1;                         \
    }                                                                         \
    /* lgkm-only barrier: Q reads + P writes drained; kf prefetch stays in flight */ \
    asm volatile("s_waitcnt lgkmcnt(0)" ::: "memory");                        \
    __builtin_amdgcn_s_barrier();                                             \
    /* PV: A = P[32x128] from swizzled LDS, B = this wave's 32-wide d-slice (regs) */ \
    {                                                                         \
        const char* pbC = Pb + (jt & 1) * 8192;                               \
        const int sw2 = (col & 7) << 4;                                       \
        __builtin_amdgcn_s_setprio(1);                                        \
        _Pragma("unroll")                                                     \
        for (int rsub = 0; rsub < 2; ++rsub) {                                \
            const char* base = pbC + (rsub * 16 + col) * 256;                 \
            half8 af[4];                                                      \
            _Pragma("unroll")                                                 \
            for (int k0 = 0; k0 < 4; ++k0)                                    \
                af[k0] = *(const half8*)(base + ((k0 * 64 + quad * 16) ^ sw2)); \
            _Pragma("unroll")                                                 \
            for (int k0 = 0; k0 < 4; ++k0) {                                  \
                acc[rsub * 2 + 0] = __builtin_amdgcn_mfma_f32_16x16x32_f16(af[k0], vf[k0],     acc[rsub * 2 + 0], 0, 0, 0); \
                acc[rsub * 2 + 1] = __builtin_amdgcn_mfma_f32_16x16x32_f16(af[k0], vf[4 + k0], acc[rsub * 2 + 1], 0, 0, 0); \
            }                                                                 \
        }                                                                     \
        __builtin_amdgcn_s_setprio(0);                                        \
    }                                                                         \
}

__global__ __launch_bounds__(512, 4) void mlstm_kernel(
    const _Float16* __restrict__ Qh, const _Float16* __restrict__ Kh,
    const _Float16* __restrict__ Vt,
    const float* __restrict__ ig, const float* __restrict__ fg,
    const float* __restrict__ rms_scale, float* __restrict__ out)
{
    __shared__ __align__(16) char SMEM[SMB];
    char*  qlds  = SMEM;                             // [16][1024 B] Q fragments
    char*  Pb    = SMEM + OFF_PB;                    // [2][32][256 B] halfs, swizzled
    float* sG    = (float*)(SMEM + OFF_G);           // [S]  g*log2e
    float* amM2  = (float*)(SMEM + OFF_A2);          // [32] (A-M)*log2e, own rows
    float* sM2   = (float*)(SMEM + OFF_M2);          // [32] M, own rows
    float* rsumP = (float*)(SMEM + OFF_RS);          // [8][32]
    float* ssP   = (float*)(SMEM + OFF_SS);          // [8][32]
    float* wred  = (float*)(SMEM + OFF_WR);          // [8]
    float* wred2 = wred + 8;                         // [8]

    const int z  = blockIdx.x;
    const int bh = z & 7;                 // one head per XCD
    const int s_ = z >> 3;                // 0..63
    const int rb = (s_ < 32) ? s_ : 63 - (s_ - 32);   // complementary light/heavy order
    const int b  = bh >> 2, h = bh & 3;
    const int t  = threadIdx.x;
    const int w  = t >> 6;                // 0..7: QK k-group (16) / PV d-slice (32)
    const int l  = t & 63;
    const int col  = l & 15;
    const int quad = l >> 4;
    constexpr float LOG2E = 1.4426950408889634f;

    const int rowbase = rb * 32;
    const int Tt = (rb >> 2) + 1;          // KVBLK=128 causal tile count

    // ---- scan prologue: wave-level shfl scans; sG full, amM/M compact (own 32 rows) ----
    {
        const float* fgp = fg + (size_t)bh * S_;
        const float* igp = ig + (size_t)bh * S_;
        float4 fx = *(const float4*)(fgp + t * 4);
        float4 ix = *(const float4*)(igp + t * 4);
        float xi[4] = {fx.x, fx.y, fx.z, fx.w};
        float gi[4] = {ix.x, ix.y, ix.z, ix.w};
        float ls[4];
        float run = 0.f;
        #pragma unroll
        for (int i = 0; i < 4; ++i) {
            float x = xi[i];
            float lg = (x >= 0.f) ? -log1pf(expf(-x)) : (x - log1pf(expf(x)));
            run += lg;
            ls[i] = run;
        }
        const float own = run;
        #pragma unroll
        for (int m = 1; m < 64; m <<= 1) {
            float o = __shfl_up(run, m);
            if (l >= m) run += o;
        }
        if (l == 63) wred[w] = run;
        __syncthreads();
        float wpre = 0.f;
        for (int ww = 0; ww < w; ++ww) wpre += wred[ww];
        const float exclT = wpre + run - own;
        float A[4], g[4], gm[4];
        float rmax = -__builtin_inff();
        #pragma unroll
        for (int i = 0; i < 4; ++i) {
            A[i] = exclT + ls[i];
            g[i] = gi[i] - A[i];
            rmax = fmaxf(rmax, g[i]);
            gm[i] = rmax;
        }
        float sm = rmax;
        #pragma unroll
        for (int m = 1; m < 64; m <<= 1) {
            float o = __shfl_up(sm, m);
            if (l >= m) sm = fmaxf(sm, o);
        }
        if (l == 63) wred2[w] = sm;
        __syncthreads();
        float exm = -__builtin_inff();
        for (int ww = 0; ww < w; ++ww) exm = fmaxf(exm, wred2[ww]);
        float up = __shfl_up(sm, 1);
        if (l > 0) exm = fmaxf(exm, up);
        #pragma unroll
        for (int i = 0; i < 4; ++i) {
            float cm = fmaxf(exm, gm[i]);
            float Mi = A[i] + cm;
            const int r = t * 4 + i;
            sG[r] = g[i] * LOG2E;
            if ((r >> 5) == rb) {
                amM2[r & 31] = (A[i] - Mi) * LOG2E;
                sM2[r & 31]  = Mi;
            }
        }
        __syncthreads();
    }

    const _Float16* Qp  = Qh + (size_t)bh * S_ * HD_;
    const _Float16* Kp  = Kh + (size_t)bh * S_ * HD_;
    const _Float16* Vtp = Vt + (size_t)bh * HD_ * S_;

    half8 kf[8], vf[8];

    // stage Q tile (16 frags x 1 KB) into LDS: 512 threads x 2 x 16 B
    {
        const int f0 = t >> 6, lo = t & 63;
        const _Float16* q0s = Qp + ((size_t)(rb * 16 + f0)) * 512 + lo * 8;
        *(half8*)(qlds + f0 * 1024 + lo * 16) = *(const half8*)q0s;
        *(half8*)(qlds + (f0 + 8) * 1024 + lo * 16) = *(const half8*)(q0s + 8 * 512);
    }
    // preload tile-0 K (this wave's exclusive 16 K-rows); stays in flight across barrier
    {
        const _Float16* kb_ = Kp + ((size_t)(w * 8)) * 512 + l * 8;
        #pragma unroll
        for (int kk = 0; kk < 8; ++kk)
            kf[kk] = *(const half8*)(kb_ + kk * 512);
    }
    const float amM0 = amM2[col];
    const float amM1 = amM2[16 + col];

    f32x4 acc[4];
    #pragma unroll
    for (int i = 0; i < 4; ++i) acc[i] = (f32x4){0.f, 0.f, 0.f, 0.f};
    float rs0 = 0.f, rs1 = 0.f;

    // qlds staged (ds writes) -> lgkm-only barrier keeps kf loads in flight
    asm volatile("s_waitcnt lgkmcnt(0)" ::: "memory");
    __builtin_amdgcn_s_barrier();

    int jt = 0;
    for (; jt + 1 < Tt; ++jt) { TILE_BODY(false); }
    TILE_BODY(true);

    // ---- epilogue: rowsum across 8 k-waves, normalize, RMSNorm, store d-slice ----
    rs0 += __shfl_xor(rs0, 16); rs0 += __shfl_xor(rs0, 32);
    rs1 += __shfl_xor(rs1, 16); rs1 += __shfl_xor(rs1, 32);
    if (quad == 0) {
        rsumP[w * 32 + col]      = rs0;
        rsumP[w * 32 + 16 + col] = rs1;
    }
    __syncthreads();
    float inv0[4], inv1[4];
    #pragma unroll
    for (int rr = 0; rr < 4; ++rr) {
        const int r0 = quad * 4 + rr;
        float tot0 = 0.f, tot1 = 0.f;
        #pragma unroll
        for (int ww = 0; ww < 8; ++ww) {
            tot0 += rsumP[ww * 32 + r0];
            tot1 += rsumP[ww * 32 + 16 + r0];
        }
        float M0 = sM2[r0];
        float M1 = sM2[16 + r0];
        inv0[rr] = 1.0f / (fmaxf(tot0, __expf(-M0)) + 1e-6f);
        inv1[rr] = 1.0f / (fmaxf(tot1, __expf(-M1)) + 1e-6f);
    }
    float ss0[4] = {0.f,0.f,0.f,0.f}, ss1[4] = {0.f,0.f,0.f,0.f};
    #pragma unroll
    for (int dn = 0; dn < 2; ++dn) {
        #pragma unroll
        for (int rr = 0; rr < 4; ++rr) {
            float h0 = acc[dn][rr] * inv0[rr];
            acc[dn][rr] = h0;
            ss0[rr] = fmaf(h0, h0, ss0[rr]);
            float h1 = acc[2 + dn][rr] * inv1[rr];
            acc[2 + dn][rr] = h1;
            ss1[rr] = fmaf(h1, h1, ss1[rr]);
        }
    }
    #pragma unroll
    for (int m = 1; m < 16; m <<= 1) {
        #pragma unroll
        for (int rr = 0; rr < 4; ++rr) {
            ss0[rr] += __shfl_xor(ss0[rr], m);
            ss1[rr] += __shfl_xor(ss1[rr], m);
        }
    }
    if (col == 0) {
        #pragma unroll
        for (int rr = 0; rr < 4; ++rr) {
            ssP[w * 32 + quad * 4 + rr]      = ss0[rr];
            ssP[w * 32 + 16 + quad * 4 + rr] = ss1[rr];
        }
    }
    __syncthreads();
    const float rsc0 = 1.f + rms_scale[w * 32 + col];
    const float rsc1 = 1.f + rms_scale[w * 32 + 16 + col];
    #pragma unroll
    for (int rr = 0; rr < 4; ++rr) {
        const int r0 = quad * 4 + rr;
        float sst0 = 0.f, sst1 = 0.f;
        #pragma unroll
        for (int ww = 0; ww < 8; ++ww) {
            sst0 += ssP[ww * 32 + r0];
            sst1 += ssP[ww * 32 + 16 + r0];
        }
        float rstd0 = rsqrtf(sst0 * (1.0f / HD_) + 1e-6f);
        float rstd1 = rsqrtf(sst1 * (1.0f / HD_) + 1e-6f);
        float* o0 = out + ((size_t)(b * S_ + rowbase + r0)) * E_ + h * HD_ + w * 32;
        float* o1 = out + ((size_t)(b * S_ + rowbase + 16 + r0)) * E_ + h * HD_ + w * 32;
        o0[col]      = acc[0][rr] * rstd0 * rsc0;
        o0[16 + col] = acc[1][rr] * rstd0 * rsc1;
        o1[col]      = acc[2][rr] * rstd1 * rsc0;
        o1[16 + col] = acc[3][rr] * rstd1 * rsc1;
    }
}

extern "C" void kernel_launch(void* const* d_in, const int* in_sizes, int n_in,
                              void* d_out, int out_size, void* d_ws, size_t ws_size,
                              hipStream_t stream) {
    (void)in_sizes; (void)n_in; (void)out_size; (void)ws_size;
    const float* q   = (const float*)d_in[0];
    const float* k   = (const float*)d_in[1];
    const float* v   = (const float*)d_in[2];
    const float* igk = (const float*)d_in[3];
    const float* igb = (const float*)d_in[4];
    const float* fgk = (const float*)d_in[5];
    const float* fgb = (const float*)d_in[6];
    const float* rsc = (const float*)d_in[7];
    float* out = (float*)d_out;

    float* ws  = (float*)d_ws;
    float* ig  = ws;                          // BH*S each
    float* fg  = ws + (size_t)BH_ * S_;
    _Float16* Qh = (_Float16*)(ws + (size_t)2 * BH_ * S_);
    _Float16* Kh = Qh + (size_t)BH_ * S_ * HD_;
    _Float16* Vt = Kh + (size_t)BH_ * S_ * HD_;

    prep_kernel<<<B_ * S_ / 16, 1024, 0, stream>>>(q, k, v, igk, igb, fgk, fgb,
                                                   ig, fg, Qh, Kh, Vt);
    mlstm_kernel<<<BH_ * 64, 512, 0, stream>>>(Qh, Kh, Vt, ig, fg, rsc, out);
}

// Round 11
// 152.798 us; speedup vs baseline: 1.1728x; 1.1728x over previous
//
#include <hip/hip_runtime.h>
#include <math.h>

static constexpr int B_  = 2;
static constexpr int S_  = 2048;
static constexpr int E_  = 1024;
static constexpr int NH_ = 4;
static constexpr int HD_ = 256;
static constexpr int BH_ = B_ * NH_;

typedef __attribute__((ext_vector_type(8))) _Float16 half8;
typedef __attribute__((ext_vector_type(4))) float    f32x4;
typedef __attribute__((ext_vector_type(4))) _Float16 half4v;

// Fragment-major layouts (written by prep, read by mlstm as coalesced 1 KB lines):
//  Q/K per bh: frag(rb16 = s>>4, kk = d>>5) at ((rb16*8 + kk)*512) halfs;
//              lane l = (s&15) + (((d&31)>>3)<<4) holds halfs j = d&7.
//  V^T per bh: frag(ktile = s>>6, dblk = d>>4, kb = (s&63)>>5) at
//              (((ktile*16 + dblk)*2 + kb)*512) halfs; lane l = (d&15) + (((s&31)>>3)<<4), j = s&7.

__device__ __forceinline__ int wofs(int e) { return (e << 4) ^ ((e & 0x38) << 1); }

// ---------------- Kernel 1: gates + fp16 Q/K (frag-major) + V frag-transpose (unchanged) ----------------
__global__ __launch_bounds__(1024) void prep_kernel(
    const float* __restrict__ q, const float* __restrict__ k, const float* __restrict__ v,
    const float* __restrict__ igk, const float* __restrict__ igb,
    const float* __restrict__ fgk, const float* __restrict__ fgb,
    float* __restrict__ ig_out, float* __restrict__ fg_out,
    _Float16* __restrict__ Qh, _Float16* __restrict__ Kh, _Float16* __restrict__ Vt)
{
    __shared__ __align__(16) char PSM[98304];
    char* wiB = PSM;            // 48 KB, swizzled float4 per element
    char* wfB = PSM + 49152;

    const int t = threadIdx.x;
    #pragma unroll
    for (int i = 0; i < 3; ++i) {
        int e = t + 1024 * i;
        *(float4*)(wiB + wofs(e)) = ((const float4*)igk)[e];
        *(float4*)(wfB + wofs(e)) = ((const float4*)fgk)[e];
    }
    __syncthreads();

    const int wave = t >> 6;
    const int l    = t & 63;
    const int bs   = blockIdx.x * 16 + wave;     // b*S + s
    const int b = bs >> 11, s = bs & (S_ - 1);
    const float* qrow = q + (size_t)bs * E_;
    const float* krow = k + (size_t)bs * E_;
    const float* vrow = v + (size_t)bs * E_;

    float accI[4] = {0.f,0.f,0.f,0.f}, accF[4] = {0.f,0.f,0.f,0.f};
    #pragma unroll
    for (int j = 0; j < 12; ++j) {
        const int e4 = l * 4 + 256 * j;          // 4 consecutive elements of gate_in
        float4 g4;
        if (j < 4)       g4 = *(const float4*)(qrow + e4);
        else if (j < 8)  g4 = *(const float4*)(krow + (e4 - E_));
        else             g4 = *(const float4*)(vrow + (e4 - 2 * E_));
        const float ge[4] = {g4.x, g4.y, g4.z, g4.w};
        if (j < 4) {
            const int d = e4 & 255, hh = e4 >> 8;
            const int idx = ((s >> 4) * 8 + (d >> 5)) * 512
                          + (s & 15) * 8 + (((d & 31) >> 3) << 7) + (d & 7);
            half4v st;
            st.x = (_Float16)(ge[0] * 0.0625f); st.y = (_Float16)(ge[1] * 0.0625f);
            st.z = (_Float16)(ge[2] * 0.0625f); st.w = (_Float16)(ge[3] * 0.0625f);
            *(half4v*)(Qh + ((size_t)(b * NH_ + hh)) * (S_ * HD_) + idx) = st;
        } else if (j < 8) {
            const int e2 = e4 - E_;
            const int d = e2 & 255, hh = e2 >> 8;
            const int idx = ((s >> 4) * 8 + (d >> 5)) * 512
                          + (s & 15) * 8 + (((d & 31) >> 3) << 7) + (d & 7);
            half4v st;
            st.x = (_Float16)ge[0]; st.y = (_Float16)ge[1];
            st.z = (_Float16)ge[2]; st.w = (_Float16)ge[3];
            *(half4v*)(Kh + ((size_t)(b * NH_ + hh)) * (S_ * HD_) + idx) = st;
        }
        #pragma unroll
        for (int i = 0; i < 4; ++i) {
            float4 wiv = *(const float4*)(wiB + wofs(e4 + i));
            float4 wfv = *(const float4*)(wfB + wofs(e4 + i));
            accI[0] = fmaf(ge[i], wiv.x, accI[0]); accI[1] = fmaf(ge[i], wiv.y, accI[1]);
            accI[2] = fmaf(ge[i], wiv.z, accI[2]); accI[3] = fmaf(ge[i], wiv.w, accI[3]);
            accF[0] = fmaf(ge[i], wfv.x, accF[0]); accF[1] = fmaf(ge[i], wfv.y, accF[1]);
            accF[2] = fmaf(ge[i], wfv.z, accF[2]); accF[3] = fmaf(ge[i], wfv.w, accF[3]);
        }
    }
    #pragma unroll
    for (int m = 1; m < 64; m <<= 1) {
        #pragma unroll
        for (int h = 0; h < 4; ++h) {
            accI[h] += __shfl_xor(accI[h], m);
            accF[h] += __shfl_xor(accF[h], m);
        }
    }
    if (l == 0) {
        #pragma unroll
        for (int h = 0; h < 4; ++h) {
            ig_out[((size_t)(b * NH_ + h)) * S_ + s] = accI[h] + igb[h];
            fg_out[((size_t)(b * NH_ + h)) * S_ + s] = accF[h] + fgb[h];
        }
    }

    __syncthreads();    // all weight reads done; reuse LDS for V transpose
    {
        float (*tile)[65] = (float(*)[65])(PSM + (t >> 8) * 16640);
        const int tid = t & 255;
        const int m  = blockIdx.x * 4 + (t >> 8);    // 0..1023 tile jobs
        const int bh = m & 7;
        const int sb = (m >> 3) & 31;                // ktile
        const int db = m >> 8;                       // d block of 64
        const int bb = bh >> 2, hh = bh & 3;
        const int j4 = (tid & 15) * 4;
        const int i0 = tid >> 4;
        const float* src = v + ((size_t)(bb * S_ + sb * 64)) * E_ + hh * HD_ + db * 64;
        #pragma unroll
        for (int p = 0; p < 4; ++p) {
            int i = i0 + p * 16;
            float4 val = *(const float4*)(src + (size_t)i * E_ + j4);
            tile[i][j4] = val.x; tile[i][j4+1] = val.y; tile[i][j4+2] = val.z; tile[i][j4+3] = val.w;
        }
        __syncthreads();
        const int ll = tid & 63;
        const int sw_ = tid >> 6;
        _Float16* dstb = Vt + (size_t)bh * (S_ * HD_);
        #pragma unroll
        for (int kb = 0; kb < 2; ++kb) {
            half8 pk;
            #pragma unroll
            for (int jj = 0; jj < 8; ++jj)
                pk[jj] = (_Float16)tile[kb * 32 + (ll >> 4) * 8 + jj][sw_ * 16 + (ll & 15)];
            *(half8*)(dstb + ((size_t)((sb * 16 + db * 4 + sw_) * 2 + kb)) * 512 + ll * 8) = pk;
        }
    }
}

// ---------------- Kernel 2 (R11 = R7 + NT out stores): 1 block/CU pass-fused, single-buffer K ----------------
// R8/R10 post-mortem closed the TLP question: any >=4 waves/SIMD config (512,4 / 1024) caps
// arch VGPRs at 64 (allocator splits 128 unified into 64 arch + 64 acc) -> this kernel's
// ~100 arch-reg operand footprint spills (3x reproduced: R2, R8, R10). R9 showed V-via-LDS
// costs more LDS bandwidth (+1K cy/tile) than the latency it hides at 2 waves/SIMD.
// R7 is therefore the measured optimum of the explored space: zero-duplication KVBLK=128
// wave decomposition, K/V/Q in regs, P-only LDS (swizzled, dbuf), lgkm-only barrier,
// pass-fused {u, 63-u} (uniform 17 tiles/block). R11 adds only non-temporal out stores
// (keep the head's 3 MB K/V resident in the 4 MB XCD L2 against the 2 MB out stream).
static constexpr int OFF_AMM = 16384;                  // P dbuf [2][32 rows][256 B]
static constexpr int OFF_G   = OFF_AMM + S_ * 4;       // 24576
static constexpr int OFF_M   = OFF_G + S_ * 4;         // 32768
static constexpr int OFF_RS  = OFF_M + S_ * 4;         // 40960: [8][32] floats
static constexpr int OFF_SS  = OFF_RS + 1024;          // 41984
static constexpr int OFF_WR  = OFF_SS + 1024;          // 43008
static constexpr int SMB     = OFF_WR + 64;            // 43072

#define TILE_BODY(MASKED)                                                     \
{                                                                             \
    /* V fragments for THIS tile (consumed after the barrier) */              \
    {                                                                         \
        const _Float16* vb_ = Vtp + (size_t)jt * 32768 + l * 8;               \
        _Pragma("unroll")                                                     \
        for (int dn = 0; dn < 2; ++dn) {                                      \
            _Pragma("unroll")                                                 \
            for (int k0 = 0; k0 < 4; ++k0)                                    \
                vf[dn * 4 + k0] = *(const half8*)(vb_                         \
                    + (((k0 >> 1) * 16 + w * 2 + dn) * 2 + (k0 & 1)) * 512);  \
        }                                                                     \
    }                                                                         \
    /* swapped QK^T: D[k][q], col=lane&15 is q-row, row=quad*4+rr is k */     \
    f32x4 s0 = (f32x4){0.f,0.f,0.f,0.f}, s1 = (f32x4){0.f,0.f,0.f,0.f};      \
    __builtin_amdgcn_s_setprio(1);                                            \
    _Pragma("unroll")                                                         \
    for (int kk = 0; kk < 8; ++kk) {                                          \
        s0 = __builtin_amdgcn_mfma_f32_16x16x32_f16(kf[kk], qf0[kk], s0, 0, 0, 0); \
        s1 = __builtin_amdgcn_mfma_f32_16x16x32_f16(kf[kk], qf1[kk], s1, 0, 0, 0); \
    }                                                                         \
    __builtin_amdgcn_s_setprio(0);                                            \
    /* refill kf (same regs) for NEXT tile; stays in flight across barrier */ \
    if (!MASKED) {                                                            \
        const _Float16* kb_ = Kp + ((size_t)((jt + 1) * 8 + w) * 8) * 512 + l * 8; \
        _Pragma("unroll")                                                     \
        for (int kk = 0; kk < 8; ++kk)                                        \
            kf[kk] = *(const half8*)(kb_ + kk * 512);                         \
    }                                                                         \
    /* fixup: p = s * exp2(amM[q] + G2[k]); mask only on diagonal tile */     \
    {                                                                         \
        float4 gv4 = *(const float4*)(sG + jt * 128 + w * 16 + quad * 4);     \
        const float gvv[4] = {gv4.x, gv4.y, gv4.z, gv4.w};                    \
        char* pbC = Pb + buf * 8192;                                          \
        half4v h0, h1;                                                        \
        _Pragma("unroll")                                                     \
        for (int rr = 0; rr < 4; ++rr) {                                      \
            float p0 = s0[rr] * __builtin_amdgcn_exp2f(amM0 + gvv[rr]);       \
            float p1 = s1[rr] * __builtin_amdgcn_exp2f(amM1 + gvv[rr]);       \
            if (MASKED) {                                                     \
                const int gc = jt * 128 + w * 16 + quad * 4 + rr;             \
                p0 = (gc <= rowbase + col) ? p0 : 0.f;                        \
                p1 = (gc <= rowbase + 16 + col) ? p1 : 0.f;                   \
            }                                                                 \
            rs0 += p0; rs1 += p1;                                             \
            h0[rr] = (_Float16)p0; h1[rr] = (_Float16)p1;                     \
        }                                                                     \
        const int wb = (w * 32 + quad * 8) ^ ((col & 7) << 4);                \
        *(half4v*)(pbC + col * 256 + wb) = h0;                                \
        *(half4v*)(pbC + (16 + col) * 256 + wb) = h1;                         \
    }                                                                         \
    /* lgkm-only barrier: P ds ops drained, global prefetches stay in flight */ \
    asm volatile("s_waitcnt lgkmcnt(0)" ::: "memory");                        \
    __builtin_amdgcn_s_barrier();                                             \
    /* PV: A = P[32x128] from swizzled LDS, B = this wave's 32-wide d-slice */ \
    {                                                                         \
        const char* pbC = Pb + buf * 8192;                                    \
        const int sw2 = (col & 7) << 4;                                       \
        __builtin_amdgcn_s_setprio(1);                                        \
        _Pragma("unroll")                                                     \
        for (int rsub = 0; rsub < 2; ++rsub) {                                \
            const char* base = pbC + (rsub * 16 + col) * 256;                 \
            half8 af[4];                                                      \
            _Pragma("unroll")                                                 \
            for (int k0 = 0; k0 < 4; ++k0)                                    \
                af[k0] = *(const half8*)(base + ((k0 * 64 + quad * 16) ^ sw2)); \
            _Pragma("unroll")                                                 \
            for (int k0 = 0; k0 < 4; ++k0) {                                  \
                acc[rsub * 2 + 0] = __builtin_amdgcn_mfma_f32_16x16x32_f16(af[k0], vf[k0],     acc[rsub * 2 + 0], 0, 0, 0); \
                acc[rsub * 2 + 1] = __builtin_amdgcn_mfma_f32_16x16x32_f16(af[k0], vf[4 + k0], acc[rsub * 2 + 1], 0, 0, 0); \
            }                                                                 \
        }                                                                     \
        __builtin_amdgcn_s_setprio(0);                                        \
    }                                                                         \
    buf ^= 1;                                                                 \
}

__global__ __launch_bounds__(512, 2) void mlstm_kernel(
    const _Float16* __restrict__ Qh, const _Float16* __restrict__ Kh,
    const _Float16* __restrict__ Vt,
    const float* __restrict__ ig, const float* __restrict__ fg,
    const float* __restrict__ rms_scale, float* __restrict__ out)
{
    __shared__ __align__(16) char SMEM[SMB];
    char*  Pb    = SMEM;                             // [2][32][256 B] halfs, swizzled
    float* sAmM  = (float*)(SMEM + OFF_AMM);         // [S]  (A-M)*log2e
    float* sG    = (float*)(SMEM + OFF_G);           // [S]  g*log2e
    float* sM    = (float*)(SMEM + OFF_M);           // [S]  M
    float* rsumP = (float*)(SMEM + OFF_RS);          // [8][32]
    float* ssP   = (float*)(SMEM + OFF_SS);          // [8][32]
    float* wred  = (float*)(SMEM + OFF_WR);
    float* wred2 = wred + 8;

    const int z  = blockIdx.x;
    const int bh = z & 7;                 // one head per XCD
    const int u  = z >> 3;                // 0..31; block owns row-blocks {u, 63-u}
    const int b  = bh >> 2, h = bh & 3;
    const int t  = threadIdx.x;
    const int w  = t >> 6;                // 0..7: QK k-group (16) / PV d-slice (32)
    const int l  = t & 63;
    const int col  = l & 15;
    const int quad = l >> 4;
    constexpr float LOG2E = 1.4426950408889634f;

    // ---- scan prologue: wave-level shfl scans ----
    {
        const float* fgp = fg + (size_t)bh * S_;
        const float* igp = ig + (size_t)bh * S_;
        float4 fx = *(const float4*)(fgp + t * 4);
        float4 ix = *(const float4*)(igp + t * 4);
        float xi[4] = {fx.x, fx.y, fx.z, fx.w};
        float gi[4] = {ix.x, ix.y, ix.z, ix.w};
        float ls[4];
        float run = 0.f;
        #pragma unroll
        for (int i = 0; i < 4; ++i) {
            float x = xi[i];
            float lg = (x >= 0.f) ? -log1pf(expf(-x)) : (x - log1pf(expf(x)));
            run += lg;
            ls[i] = run;
        }
        const float own = run;
        #pragma unroll
        for (int m = 1; m < 64; m <<= 1) {
            float o = __shfl_up(run, m);
            if (l >= m) run += o;
        }
        if (l == 63) wred[w] = run;
        __syncthreads();
        float wpre = 0.f;
        for (int ww = 0; ww < w; ++ww) wpre += wred[ww];
        const float exclT = wpre + run - own;
        float A[4], g[4], gm[4];
        float rmax = -__builtin_inff();
        #pragma unroll
        for (int i = 0; i < 4; ++i) {
            A[i] = exclT + ls[i];
            g[i] = gi[i] - A[i];
            rmax = fmaxf(rmax, g[i]);
            gm[i] = rmax;
        }
        float sm = rmax;
        #pragma unroll
        for (int m = 1; m < 64; m <<= 1) {
            float o = __shfl_up(sm, m);
            if (l >= m) sm = fmaxf(sm, o);
        }
        if (l == 63) wred2[w] = sm;
        __syncthreads();
        float exm = -__builtin_inff();
        for (int ww = 0; ww < w; ++ww) exm = fmaxf(exm, wred2[ww]);
        float up = __shfl_up(sm, 1);
        if (l > 0) exm = fmaxf(exm, up);
        #pragma unroll
        for (int i = 0; i < 4; ++i) {
            float cm = fmaxf(exm, gm[i]);
            float Mi = A[i] + cm;
            sAmM[t * 4 + i] = (A[i] - Mi) * LOG2E;
            sG[t * 4 + i]   = g[i] * LOG2E;
            sM[t * 4 + i]   = Mi;
        }
        __syncthreads();
    }

    const _Float16* Qp  = Qh + (size_t)bh * S_ * HD_;
    const _Float16* Kp  = Kh + (size_t)bh * S_ * HD_;
    const _Float16* Vtp = Vt + (size_t)bh * HD_ * S_;

    half8 kf[8], vf[8];

    for (int pass = 0; pass < 2; ++pass) {
        const int rb = pass ? (63 - u) : u;
        const int rowbase = rb * 32;
        const int Tt = (rb >> 2) + 1;          // KVBLK=128 causal tile count

        // Q fragments: both 16-row halves (64 VGPR), reused across all tiles
        half8 qf0[8], qf1[8];
        {
            const _Float16* qb0 = Qp + ((size_t)(rb * 2) * 8) * 512 + l * 8;
            const _Float16* qb1 = Qp + ((size_t)(rb * 2 + 1) * 8) * 512 + l * 8;
            #pragma unroll
            for (int kk = 0; kk < 8; ++kk) {
                qf0[kk] = *(const half8*)(qb0 + kk * 512);
                qf1[kk] = *(const half8*)(qb1 + kk * 512);
            }
        }
        // swapped-QK: lane&15 = q-row; amM is per-lane scalar, loop-invariant
        const float amM0 = sAmM[rowbase + col];
        const float amM1 = sAmM[rowbase + 16 + col];

        f32x4 acc[4];
        #pragma unroll
        for (int i = 0; i < 4; ++i) acc[i] = (f32x4){0.f, 0.f, 0.f, 0.f};
        float rs0 = 0.f, rs1 = 0.f;

        // preload tile-0 K (this wave's exclusive 16 K-rows)
        {
            const _Float16* kb_ = Kp + ((size_t)(w * 8)) * 512 + l * 8;
            #pragma unroll
            for (int kk = 0; kk < 8; ++kk)
                kf[kk] = *(const half8*)(kb_ + kk * 512);
        }

        int buf = 0;
        for (int jt = 0; jt + 1 < Tt; ++jt) { TILE_BODY(false); }
        { const int jt = Tt - 1; TILE_BODY(true); }

        // ---- epilogue: rowsum across 8 k-waves, normalize, RMSNorm, store d-slice ----
        rs0 += __shfl_xor(rs0, 16); rs0 += __shfl_xor(rs0, 32);
        rs1 += __shfl_xor(rs1, 16); rs1 += __shfl_xor(rs1, 32);
        if (quad == 0) {
            rsumP[w * 32 + col]      = rs0;
            rsumP[w * 32 + 16 + col] = rs1;
        }
        __syncthreads();
        float inv0[4], inv1[4];
        #pragma unroll
        for (int rr = 0; rr < 4; ++rr) {
            const int r0 = quad * 4 + rr;
            float tot0 = 0.f, tot1 = 0.f;
            #pragma unroll
            for (int ww = 0; ww < 8; ++ww) {
                tot0 += rsumP[ww * 32 + r0];
                tot1 += rsumP[ww * 32 + 16 + r0];
            }
            float M0 = sM[rowbase + r0];
            float M1 = sM[rowbase + 16 + r0];
            inv0[rr] = 1.0f / (fmaxf(tot0, __expf(-M0)) + 1e-6f);
            inv1[rr] = 1.0f / (fmaxf(tot1, __expf(-M1)) + 1e-6f);
        }
        float ss0[4] = {0.f,0.f,0.f,0.f}, ss1[4] = {0.f,0.f,0.f,0.f};
        #pragma unroll
        for (int dn = 0; dn < 2; ++dn) {
            #pragma unroll
            for (int rr = 0; rr < 4; ++rr) {
                float h0 = acc[dn][rr] * inv0[rr];
                acc[dn][rr] = h0;
                ss0[rr] = fmaf(h0, h0, ss0[rr]);
                float h1 = acc[2 + dn][rr] * inv1[rr];
                acc[2 + dn][rr] = h1;
                ss1[rr] = fmaf(h1, h1, ss1[rr]);
            }
        }
        #pragma unroll
        for (int m = 1; m < 16; m <<= 1) {
            #pragma unroll
            for (int rr = 0; rr < 4; ++rr) {
                ss0[rr] += __shfl_xor(ss0[rr], m);
                ss1[rr] += __shfl_xor(ss1[rr], m);
            }
        }
        if (col == 0) {
            #pragma unroll
            for (int rr = 0; rr < 4; ++rr) {
                ssP[w * 32 + quad * 4 + rr]      = ss0[rr];
                ssP[w * 32 + 16 + quad * 4 + rr] = ss1[rr];
            }
        }
        __syncthreads();
        const float rsc0 = 1.f + rms_scale[w * 32 + col];
        const float rsc1 = 1.f + rms_scale[w * 32 + 16 + col];
        #pragma unroll
        for (int rr = 0; rr < 4; ++rr) {
            const int r0 = quad * 4 + rr;
            float sst0 = 0.f, sst1 = 0.f;
            #pragma unroll
            for (int ww = 0; ww < 8; ++ww) {
                sst0 += ssP[ww * 32 + r0];
                sst1 += ssP[ww * 32 + 16 + r0];
            }
            float rstd0 = rsqrtf(sst0 * (1.0f / HD_) + 1e-6f);
            float rstd1 = rsqrtf(sst1 * (1.0f / HD_) + 1e-6f);
            float* o0 = out + ((size_t)(b * S_ + rowbase + r0)) * E_ + h * HD_ + w * 32;
            float* o1 = out + ((size_t)(b * S_ + rowbase + 16 + r0)) * E_ + h * HD_ + w * 32;
            // non-temporal: out is write-once streaming; keep K/V resident in the XCD L2
            __builtin_nontemporal_store(acc[0][rr] * rstd0 * rsc0, o0 + col);
            __builtin_nontemporal_store(acc[1][rr] * rstd0 * rsc1, o0 + 16 + col);
            __builtin_nontemporal_store(acc[2][rr] * rstd1 * rsc0, o1 + col);
            __builtin_nontemporal_store(acc[3][rr] * rstd1 * rsc1, o1 + 16 + col);
        }
        __syncthreads();   // rsumP/ssP retired before next pass reuses them
    }
}

extern "C" void kernel_launch(void* const* d_in, const int* in_sizes, int n_in,
                              void* d_out, int out_size, void* d_ws, size_t ws_size,
                              hipStream_t stream) {
    (void)in_sizes; (void)n_in; (void)out_size; (void)ws_size;
    const float* q   = (const float*)d_in[0];
    const float* k   = (const float*)d_in[1];
    const float* v   = (const float*)d_in[2];
    const float* igk = (const float*)d_in[3];
    const float* igb = (const float*)d_in[4];
    const float* fgk = (const float*)d_in[5];
    const float* fgb = (const float*)d_in[6];
    const float* rsc = (const float*)d_in[7];
    float* out = (float*)d_out;

    float* ws  = (float*)d_ws;
    float* ig  = ws;                          // BH*S each
    float* fg  = ws + (size_t)BH_ * S_;
    _Float16* Qh = (_Float16*)(ws + (size_t)2 * BH_ * S_);
    _Float16* Kh = Qh + (size_t)BH_ * S_ * HD_;
    _Float16* Vt = Kh + (size_t)BH_ * S_ * HD_;

    prep_kernel<<<B_ * S_ / 16, 1024, 0, stream>>>(q, k, v, igk, igb, fgk, fgb,
                                                   ig, fg, Qh, Kh, Vt);
    mlstm_kernel<<<BH_ * 32, 512, 0, stream>>>(Qh, Kh, Vt, ig, fg, rsc, out);
}